// Round 12
// baseline (26.722 us; speedup 1.0000x reference)
//
#include <hip/hip_runtime.h>

#define AS1 __attribute__((address_space(1)))
#define AS3 __attribute__((address_space(3)))

typedef unsigned short u16;
typedef _Float16 f16;
typedef __bf16 bf16x8 __attribute__((ext_vector_type(8)));
typedef float f32x4 __attribute__((ext_vector_type(4)));
typedef _Float16 f16x4 __attribute__((ext_vector_type(4)));
typedef unsigned short u16x8 __attribute__((ext_vector_type(8)));

// ws layout (20 MB):
//   A: [4][512][1024]  bf16(u16) @ 0      (4 MB)   A[seg][b][i] = b_seg(x[b][i])
//   W: [4][1024][1024] bf16(u16) @ 4 MB   (8 MB)   W[seg][o][i] = bf16(cp_seg[o][i])
//   P: [8][512][1024]  f16       @ 12 MB  (8 MB)   split-K partials (f16)
//
// XCD-affinity test, clean version (r10's was corrupted by uncoalesced prep):
// W rows [nb*128,+128) are written only by prep blocks with bid&7==nb and read
// only by gemm WGs with bid&7==nb; P cols [nb*128,+128) likewise. All accesses
// stay fully coalesced (contiguous 16B per lane).

__device__ __forceinline__ u16 f2bf(float f) {
    union { float f; unsigned int u; } v;
    v.f = f;
    unsigned int u = v.u;
    u += 0x7fffu + ((u >> 16) & 1u);   // RNE
    return (u16)(u >> 16);
}

// 768 blocks: b<512 -> W (XCD-affine, contiguous per block), b>=512 -> A.
__global__ __launch_bounds__(256) void prep_kernel(
    const float* __restrict__ x,
    const float* __restrict__ cp0, const float* __restrict__ cp1,
    const float* __restrict__ cp2, const float* __restrict__ cp3,
    u16* __restrict__ A, u16* __restrict__ W)
{
    const int bid = blockIdx.x;
    const int tid = threadIdx.x;
    if (bid < 512) {
        // Block (nb=bid&7, j=bid>>3): seg=j>>4, row-group rg=j&15.
        // Writes the CONTIGUOUS region W[seg][nb*128+rg*8 .. +8)[0..1024):
        // 8192 bf16 elems = 16 KB; 4 passes of 2048 elems (8/thread, adjacent).
        const int nb  = bid & 7;
        const int j   = bid >> 3;
        const int seg = j >> 4;
        const int base = (nb * 128 + (j & 15) * 8) * 1024;   // elem offset
        const float* cps[4] = {cp0, cp1, cp2, cp3};
        const float* src = cps[seg] + base;
        u16* dst = W + seg * 1048576 + base;
        #pragma unroll
        for (int p = 0; p < 4; ++p) {
            const int e = p * 2048 + tid * 8;
            float4 v0 = *(const float4*)(src + e);
            float4 v1 = *(const float4*)(src + e + 4);
            u16x8 o;
            o[0] = f2bf(v0.x); o[1] = f2bf(v0.y); o[2] = f2bf(v0.z); o[3] = f2bf(v0.w);
            o[4] = f2bf(v1.x); o[5] = f2bf(v1.y); o[6] = f2bf(v1.z); o[7] = f2bf(v1.w);
            *(u16x8*)(dst + e) = o;
        }
    } else {
        // A: 512K elems, 8 per thread (r8 verbatim).
        const int idx = ((bid - 512) * 256 + tid) * 8;
        float4 v0 = *(const float4*)(x + idx);
        float4 v1 = *(const float4*)(x + idx + 4);
        float vv[8] = {v0.x, v0.y, v0.z, v0.w, v1.x, v1.y, v1.z, v1.w};
        u16 q[4][8];
        #pragma unroll
        for (int jj = 0; jj < 8; ++jj) {
            float xx = vv[jj];
            float t = fminf(fabsf(xx), 1.0f);
            float s = 1.0f - t;
            q[0][jj] = f2bf(s * s * s * xx);
            q[1][jj] = f2bf(3.0f * s * s * t * xx);
            q[2][jj] = f2bf(3.0f * s * t * t * xx);
            q[3][jj] = f2bf(t * t * t * xx);
        }
        #pragma unroll
        for (int seg = 0; seg < 4; ++seg) {
            u16x8 o;
            #pragma unroll
            for (int jj = 0; jj < 8; ++jj) o[jj] = q[seg][jj];
            *(u16x8*)(A + seg * 524288 + idx) = o;
        }
    }
}

__device__ __forceinline__ void load16(const u16* g, u16* l) {
    __builtin_amdgcn_global_load_lds((const AS1 unsigned int*)g,
                                     (AS3 unsigned int*)l, 16, 0, 0);
}

// r8 gemm verbatim: 128x128 tile, BK=128 (4 k-steps), split-K=8, 512 threads
// (8 waves of 64x32), counted-vmcnt pipeline (never vmcnt(0) in loop),
// LDS [128][128] bf16 XOR-swizzled (pre-swizzled source, linear LDS dest).
__global__ __launch_bounds__(512) void gemm_kernel(
    const u16* __restrict__ A, const u16* __restrict__ W,
    f16* __restrict__ P)
{
    __shared__ u16 lsA[2][128 * 128];   // 32 KB per buf
    __shared__ u16 lsB[2][128 * 128];

    const int tid  = threadIdx.x;
    const int lane = tid & 63;
    const int wid  = tid >> 6;

    const int bid  = blockIdx.x;          // 0..255
    const int nb   = bid & 7;             // N-block == XCD key (local W slice)
    const int mb   = (bid >> 3) & 3;      // M-block
    const int kz   = bid >> 5;            // K-slice 0..7
    const int seg  = kz >> 1;
    const int kbase = (kz & 1) * 512;
    const int brow = mb * 128;
    const int bcol = nb * 128;

    const u16* Ag = A + seg * 524288  + brow * 1024 + kbase;
    const u16* Wg = W + seg * 1048576 + bcol * 1024 + kbase;

    int goff[4], loff[4];
    #pragma unroll
    for (int j = 0; j < 4; ++j) {
        const int c   = tid + j * 512;
        const int row = c >> 4;
        goff[j] = row * 1024 + ((c & 15) ^ (row & 15)) * 8;
        loff[j] = c * 8;
    }

    const int wr = (wid >> 2) * 64;
    const int wc = (wid & 3) * 32;
    const int fr = lane & 15;
    const int q  = lane >> 4;
    int ofs[4];
    #pragma unroll
    for (int kk = 0; kk < 4; ++kk)
        ofs[kk] = ((kk * 4 + q) ^ fr) * 16;

    f32x4 acc[4][2] = {};

    #pragma unroll
    for (int j = 0; j < 4; ++j) {
        load16(Ag + goff[j], &lsA[0][loff[j]]);
        load16(Wg + goff[j], &lsB[0][loff[j]]);
    }

    #pragma unroll
    for (int kt = 0; kt < 4; ++kt) {
        const int buf = kt & 1;
        if (kt < 3) {
            const int k0 = (kt + 1) * 128;
            #pragma unroll
            for (int j = 0; j < 4; ++j) {
                load16(Ag + k0 + goff[j], &lsA[buf ^ 1][loff[j]]);
                load16(Wg + k0 + goff[j], &lsB[buf ^ 1][loff[j]]);
            }
            asm volatile("s_waitcnt vmcnt(8)" ::: "memory");
        } else {
            asm volatile("s_waitcnt vmcnt(0)" ::: "memory");
        }
        __builtin_amdgcn_s_barrier();
        __builtin_amdgcn_sched_barrier(0);     // rule #18

        const char* bA = (const char*)lsA[buf];
        const char* bB = (const char*)lsB[buf];
        #pragma unroll
        for (int kk = 0; kk < 4; ++kk) {
            bf16x8 a[4], b[2];
            #pragma unroll
            for (int m = 0; m < 4; ++m)
                a[m] = *(const bf16x8*)(bA + (wr + m * 16 + fr) * 256 + ofs[kk]);
            #pragma unroll
            for (int n = 0; n < 2; ++n)
                b[n] = *(const bf16x8*)(bB + (wc + n * 16 + fr) * 256 + ofs[kk]);
            #pragma unroll
            for (int m = 0; m < 4; ++m)
                #pragma unroll
                for (int n = 0; n < 2; ++n)
                    acc[m][n] = __builtin_amdgcn_mfma_f32_16x16x32_bf16(
                        a[m], b[n], acc[m][n], 0, 0, 0);
        }
        __builtin_amdgcn_s_barrier();
        __builtin_amdgcn_sched_barrier(0);
    }

    f16* Pk = P + kz * 524288;
    const int cr0 = brow + wr + q * 4;
    const int cc0 = bcol + wc + fr;
    #pragma unroll
    for (int m = 0; m < 4; ++m)
        #pragma unroll
        for (int n = 0; n < 2; ++n)
            #pragma unroll
            for (int j = 0; j < 4; ++j)
                Pk[(cr0 + m * 16 + j) * 1024 + cc0 + n * 16] = (f16)acc[m][n][j];
}

// 64 blocks, XCD-affine: block (nb=bid&7, g=bid>>3) reduces rows [g*64,+64),
// cols [nb*128,+128) -- written by gemm WGs with the same nb. Fixed z order.
__global__ __launch_bounds__(256) void reduce_kernel(
    const f16* __restrict__ P, float* __restrict__ out)
{
    const int nb = blockIdx.x & 7;
    const int g  = blockIdx.x >> 3;
    const int tid = threadIdx.x;
    #pragma unroll
    for (int j = 0; j < 8; ++j) {
        const int u  = tid + j * 256;            // 2048 float4-units per tile
        const int r  = g * 64 + (u >> 5);
        const int c4 = (u & 31) * 4;
        const int off = r * 1024 + nb * 128 + c4;
        float s0 = 0.f, s1 = 0.f, s2 = 0.f, s3 = 0.f;
        #pragma unroll
        for (int z = 0; z < 8; ++z) {
            f16x4 v = *(const f16x4*)(P + z * 524288 + off);
            s0 += (float)v[0]; s1 += (float)v[1];
            s2 += (float)v[2]; s3 += (float)v[3];
        }
        float4 o; o.x = s0; o.y = s1; o.z = s2; o.w = s3;
        *(float4*)(out + off) = o;
    }
}

extern "C" void kernel_launch(void* const* d_in, const int* in_sizes, int n_in,
                              void* d_out, int out_size, void* d_ws, size_t ws_size,
                              hipStream_t stream)
{
    const float* x   = (const float*)d_in[0];
    const float* cp0 = (const float*)d_in[1];
    const float* cp1 = (const float*)d_in[2];
    const float* cp2 = (const float*)d_in[3];
    const float* cp3 = (const float*)d_in[4];

    u16*   A   = (u16*)d_ws;
    u16*   Wb  = (u16*)((char*)d_ws + (4u << 20));
    f16*   P   = (f16*)((char*)d_ws + (12u << 20));
    float* out = (float*)d_out;

    prep_kernel<<<768, 256, 0, stream>>>(x, cp0, cp1, cp2, cp3, A, Wb);
    gemm_kernel<<<256, 512, 0, stream>>>(A, Wb, P);
    reduce_kernel<<<64, 256, 0, stream>>>(P, out);
}